// Round 1
// baseline (2369.277 us; speedup 1.0000x reference)
//
#include <hip/hip_runtime.h>

#define DIM 2048
#define LEAK 0.2f

typedef __bf16 bf16x8 __attribute__((ext_vector_type(8)));
typedef float  f32x4  __attribute__((ext_vector_type(4)));
typedef unsigned int u32x4 __attribute__((ext_vector_type(4)));
typedef int    i32x4  __attribute__((ext_vector_type(4)));

static __device__ __forceinline__ unsigned short f2bf(float f) {
    unsigned int x = __float_as_uint(f);
    return (unsigned short)((x + 0x7fffu + ((x >> 16) & 1u)) >> 16);  // RNE
}
static __device__ __forceinline__ float bf2f(unsigned short h) {
    return __uint_as_float(((unsigned int)h) << 16);
}

static __device__ __forceinline__ void async16(const void* g, void* s) {
    __builtin_amdgcn_global_load_lds(
        (const __attribute__((address_space(1))) void*)g,
        (__attribute__((address_space(3))) void*)s, 16, 0, 0);
}

static __device__ __forceinline__ bf16x8 ld_bf16_frag(const char* p) {
    union { u32x4 u; bf16x8 v; } cv;
    cv.u = *(const u32x4*)p;   // ds_read_b128
    return cv.v;
}

// ---------------- prep kernels ----------------

__global__ __launch_bounds__(256) void split_kernel(
    const float* __restrict__ in,
    unsigned short* __restrict__ hi, unsigned short* __restrict__ lo) {
    int idx = blockIdx.x * 256 + threadIdx.x;
    float4 v = ((const float4*)in)[idx];
    ushort4 h, l;
    h.x = f2bf(v.x); l.x = f2bf(v.x - bf2f(h.x));
    h.y = f2bf(v.y); l.y = f2bf(v.y - bf2f(h.y));
    h.z = f2bf(v.z); l.z = f2bf(v.z - bf2f(h.z));
    h.w = f2bf(v.w); l.w = f2bf(v.w - bf2f(h.w));
    ((ushort4*)hi)[idx] = h;
    ((ushort4*)lo)[idx] = l;
}

__global__ __launch_bounds__(256) void transpose_split(
    const float* __restrict__ in,
    unsigned short* __restrict__ hiT, unsigned short* __restrict__ loT) {
    __shared__ float t[32][33];
    int bx = blockIdx.x, by = blockIdx.y;
    int tx = threadIdx.x & 31, ty4 = (threadIdx.x >> 5) << 2;
#pragma unroll
    for (int i = 0; i < 4; i++)
        t[ty4 + i][tx] = in[(size_t)(by * 32 + ty4 + i) * DIM + bx * 32 + tx];
    __syncthreads();
#pragma unroll
    for (int i = 0; i < 4; i++) {
        float v = t[tx][ty4 + i];
        size_t o = (size_t)(bx * 32 + ty4 + i) * DIM + by * 32 + tx;
        unsigned short h = f2bf(v);
        hiT[o] = h;
        loT[o] = f2bf(v - bf2f(h));
    }
}

__global__ __launch_bounds__(256) void transpose_i8(
    const float* __restrict__ in, signed char* __restrict__ outT) {
    __shared__ float t[32][33];
    int bx = blockIdx.x, by = blockIdx.y;
    int tx = threadIdx.x & 31, ty4 = (threadIdx.x >> 5) << 2;
#pragma unroll
    for (int i = 0; i < 4; i++)
        t[ty4 + i][tx] = in[(size_t)(by * 32 + ty4 + i) * DIM + bx * 32 + tx];
    __syncthreads();
#pragma unroll
    for (int i = 0; i < 4; i++)
        outT[(size_t)(bx * 32 + ty4 + i) * DIM + by * 32 + tx] =
            (signed char)t[tx][ty4 + i];
}

__global__ __launch_bounds__(256) void quant_split(
    const float* __restrict__ in,
    signed char* __restrict__ hi, signed char* __restrict__ lo) {
    int idx = blockIdx.x * 256 + threadIdx.x;
    float4 v = ((const float4*)in)[idx];
    char4 h, l;
    {
        int q = (int)rintf(v.x * 16384.f); q = q > 16383 ? 16383 : (q < -16383 ? -16383 : q);
        h.x = (signed char)(q >> 7); l.x = (signed char)(q & 127);
    }
    {
        int q = (int)rintf(v.y * 16384.f); q = q > 16383 ? 16383 : (q < -16383 ? -16383 : q);
        h.y = (signed char)(q >> 7); l.y = (signed char)(q & 127);
    }
    {
        int q = (int)rintf(v.z * 16384.f); q = q > 16383 ? 16383 : (q < -16383 ? -16383 : q);
        h.z = (signed char)(q >> 7); l.z = (signed char)(q & 127);
    }
    {
        int q = (int)rintf(v.w * 16384.f); q = q > 16383 ? 16383 : (q < -16383 ? -16383 : q);
        h.w = (signed char)(q >> 7); l.w = (signed char)(q & 127);
    }
    ((char4*)hi)[idx] = h;
    ((char4*)lo)[idx] = l;
}

// ---------------- bf16 dual-A GEMM (drive), tile 64x128, dbuf ----------------
// MODE 0: Cout = (Ahi+Alo) @ B^T        MODE 1: Cout = Cin + P + bias[n]
template <int MODE>
__global__ __launch_bounds__(256) void gemm_bf16(
    const unsigned short* __restrict__ Ahi,
    const unsigned short* __restrict__ Alo,
    const unsigned short* __restrict__ BT,
    const float* __restrict__ Cin,
    const float* __restrict__ bias,
    float* __restrict__ Cout) {
    __shared__ alignas(16) char sA[2][16384];
    __shared__ alignas(16) char sB[2][16384];

    const int bid = blockIdx.x;
    const int xcd = bid & 7, slot = bid >> 3;
    const int tm = ((xcd >> 1) << 3) + (slot >> 3);      // 0..31
    const int tn = ((xcd & 1) << 3) + (slot & 7);        // 0..15
    const int row0 = tm << 6, col0 = tn << 7;

    const int tid = threadIdx.x;
    const int lane = tid & 63;
    const int quad = lane >> 4, l16 = lane & 15;
    const int wave = tid >> 6;
    const int wm = wave >> 1, wn = wave & 1;

    const unsigned short* a_src[4]; int a_dst[4];
    const unsigned short* b_src[4]; int b_dst[4];
#pragma unroll
    for (int i = 0; i < 4; i++) {
        int s = tid + 256 * i;                 // 0..1023
        {
            int r = s >> 4, g = (s >> 3) & 1, c = (s & 7) ^ (r & 7);
            a_src[i] = (g ? Alo : Ahi) + (size_t)(row0 + r) * DIM + c * 8;
            a_dst[i] = s * 16;
        }
        {
            int r = s >> 3, c = (s & 7) ^ (r & 7);
            b_src[i] = BT + (size_t)(col0 + r) * DIM + c * 8;
            b_dst[i] = s * 16;
        }
    }

    f32x4 acc[2][4] = {};

    auto stage = [&](int p, int k0) {
#pragma unroll
        for (int i = 0; i < 4; i++) {
            async16(a_src[i] + k0, sA[p] + a_dst[i]);
            async16(b_src[i] + k0, sB[p] + b_dst[i]);
        }
    };

    stage(0, 0);
    __syncthreads();
    for (int it = 0; it < 32; it++) {          // BK = 64 elems (128B)
        const int p = it & 1;
        if (it + 1 < 32) stage(1 - p, (it + 1) * 64);
#pragma unroll
        for (int kk = 0; kk < 2; kk++) {       // two K=32 MFMA phases
            bf16x8 ah[2], al[2], bv[4];
#pragma unroll
            for (int i = 0; i < 2; i++) {
                const int r = (wm << 5) + (i << 4) + l16;
                const int cs = ((kk << 2) + quad) ^ (r & 7);
                ah[i] = ld_bf16_frag(sA[p] + ((r << 4) + cs) * 16);
                al[i] = ld_bf16_frag(sA[p] + ((r << 4) + 8 + cs) * 16);
            }
#pragma unroll
            for (int j = 0; j < 4; j++) {
                const int r = (wn << 6) + (j << 4) + l16;
                const int cs = ((kk << 2) + quad) ^ (r & 7);
                bv[j] = ld_bf16_frag(sB[p] + ((r << 3) + cs) * 16);
            }
#pragma unroll
            for (int i = 0; i < 2; i++)
#pragma unroll
                for (int j = 0; j < 4; j++) {
                    acc[i][j] = __builtin_amdgcn_mfma_f32_16x16x32_bf16(ah[i], bv[j], acc[i][j], 0, 0, 0);
                    acc[i][j] = __builtin_amdgcn_mfma_f32_16x16x32_bf16(al[i], bv[j], acc[i][j], 0, 0, 0);
                }
        }
        __syncthreads();
    }

#pragma unroll
    for (int i = 0; i < 2; i++) {
        const int rb = row0 + (wm << 5) + (i << 4) + (quad << 2);
#pragma unroll
        for (int j = 0; j < 4; j++) {
            const int c = col0 + (wn << 6) + (j << 4) + l16;
#pragma unroll
            for (int g = 0; g < 4; g++) {
                const size_t idx = (size_t)(rb + g) * DIM + c;
                if (MODE == 0) Cout[idx] = acc[i][j][g];
                else           Cout[idx] = Cin[idx] + acc[i][j][g] + bias[c];
            }
        }
    }
}

// ---------------- i8 recurrence step v2 ----------------
// Tile 128x128, grid 256 (1 block/CU), 512 threads = 8 waves.
// Wave (wm,wn,wh): output sub-tile 64x64 at (wm,wn), K-half wh (2-way K-split,
// pair-reduced through LDS at the end).  Ratio: 42.7 MFMA-ops/LDS-byte vs 32
// for the old 64x128 tile -> LDS no longer the throughput ceiling.
// Schedule: ONE raw s_barrier per K-step + counted s_waitcnt vmcnt(3)
// (stage split into two 3-load halves issued around the two 16-MFMA phases;
// prefetched loads stay in flight across the barrier -- T3+T4), setprio(1)
// around each MFMA cluster (T5).
// Race analysis: iteration `it` reads only buf[p], stages only buf[p^1];
// buf[p^1] was last read in it-1 and the top-of-it barrier orders all those
// reads (consumed before each wave's barrier arrival) before any stage issue.
__global__ __launch_bounds__(512, 2) void step_i8(
    const signed char* __restrict__ Ah,
    const signed char* __restrict__ Al,
    const signed char* __restrict__ BT,
    const float* __restrict__ drive,
    float* __restrict__ out,
    signed char* __restrict__ Oh,
    signed char* __restrict__ Ol,
    int write_f32) {
    __shared__ alignas(16) char sA[2][32768];  // 128 rows x 256B (hi 0-7 | lo 8-15 chunks), chunk^r swizzle
    __shared__ alignas(16) char sB[2][16384];  // 128 rows x 128B, swizzled

    const int bid = blockIdx.x;
    const int xcd = bid & 7, slot = bid >> 3;            // 8 XCDs x 32 slots
    const int tm = ((xcd >> 1) << 2) + (slot >> 3);      // 0..15
    const int tn = ((xcd & 1) << 3) + (slot & 7);        // 0..15
    const int row0 = tm << 7, col0 = tn << 7;

    const int tid = threadIdx.x;
    const int lane = tid & 63;
    const int quad = lane >> 4, l16 = lane & 15;
    const int wave = tid >> 6;        // 0..7
    const int wh = wave & 1;          // K-half
    const int wn = (wave >> 1) & 1;   // col 64-group
    const int wm = wave >> 2;         // row 64-group

    // staging: 6 x 16B loads/thread (4 A, 2 B), linear LDS dst, swizzled src chunk
    const signed char* a_src[4]; int a_dst[4];
    const signed char* b_src[2]; int b_dst[2];
#pragma unroll
    for (int i = 0; i < 4; i++) {
        int s = tid + 512 * i;                            // 0..2047
        int r = s >> 4, g = (s >> 3) & 1, c = (s & 7) ^ (r & 7);
        a_src[i] = (g ? Al : Ah) + (size_t)(row0 + r) * DIM + c * 16;
        a_dst[i] = s * 16;
    }
#pragma unroll
    for (int i = 0; i < 2; i++) {
        int s = tid + 512 * i;                            // 0..1023
        int r = s >> 3, c = (s & 7) ^ (r & 7);
        b_src[i] = BT + (size_t)(col0 + r) * DIM + c * 16;
        b_dst[i] = s * 16;
    }

    // per-thread constant LDS read offsets (q = K-chunk for this wave/quad)
    const int q = (wh << 2) + quad;
    int aoff[4], boff[4];
#pragma unroll
    for (int i = 0; i < 4; i++) {
        int r = (wm << 6) + (i << 4) + l16;
        aoff[i] = r * 256 + ((q ^ (r & 7)) << 4);
    }
#pragma unroll
    for (int j = 0; j < 4; j++) {
        int r = (wn << 6) + (j << 4) + l16;
        boff[j] = r * 128 + ((q ^ (r & 7)) << 4);
    }

    i32x4 acch[4][4] = {};
    i32x4 accl[4][4] = {};

    // prologue: stage buffer 0 (K bytes 0..127)
#pragma unroll
    for (int i = 0; i < 4; i++) async16(a_src[i], sA[0] + a_dst[i]);
#pragma unroll
    for (int i = 0; i < 2; i++) async16(b_src[i], sB[0] + b_dst[i]);

    for (int it = 0; it < 16; ++it) {
        const int p = it & 1;
        const char* pa = sA[p];
        const char* pb = sB[p];
        char* na = sA[p ^ 1];
        char* nb = sB[p ^ 1];
        const int k0 = (it + 1) << 7;

        __builtin_amdgcn_s_barrier();
        __builtin_amdgcn_sched_barrier(0);
        if (it + 1 < 16) {
            // stage half 0 of next buffer, then wait only for current buffer's 6 loads
            async16(a_src[0] + k0, na + a_dst[0]);
            async16(a_src[1] + k0, na + a_dst[1]);
            async16(b_src[0] + k0, nb + b_dst[0]);
            __builtin_amdgcn_sched_barrier(0);
            asm volatile("s_waitcnt vmcnt(3)" ::: "memory");
        } else {
            asm volatile("s_waitcnt vmcnt(0)" ::: "memory");
        }

        // ---- phase 0: i = 0,1 ----
        {
            i32x4 ah0 = *(const i32x4*)(pa + aoff[0]);
            i32x4 al0 = *(const i32x4*)(pa + aoff[0] + 128);
            i32x4 ah1 = *(const i32x4*)(pa + aoff[1]);
            i32x4 al1 = *(const i32x4*)(pa + aoff[1] + 128);
            i32x4 bv[4];
#pragma unroll
            for (int j = 0; j < 4; j++) bv[j] = *(const i32x4*)(pb + boff[j]);
            __builtin_amdgcn_s_setprio(1);
#pragma unroll
            for (int j = 0; j < 4; j++) {
                acch[0][j] = __builtin_amdgcn_mfma_i32_16x16x64_i8(ah0, bv[j], acch[0][j], 0, 0, 0);
                accl[0][j] = __builtin_amdgcn_mfma_i32_16x16x64_i8(al0, bv[j], accl[0][j], 0, 0, 0);
                acch[1][j] = __builtin_amdgcn_mfma_i32_16x16x64_i8(ah1, bv[j], acch[1][j], 0, 0, 0);
                accl[1][j] = __builtin_amdgcn_mfma_i32_16x16x64_i8(al1, bv[j], accl[1][j], 0, 0, 0);
            }
            __builtin_amdgcn_s_setprio(0);

            // stage half 1 of next buffer
            if (it + 1 < 16) {
                async16(a_src[2] + k0, na + a_dst[2]);
                async16(a_src[3] + k0, na + a_dst[3]);
                async16(b_src[1] + k0, nb + b_dst[1]);
            }

            // ---- phase 1: i = 2,3 (B frags reused from regs) ----
            i32x4 ah2 = *(const i32x4*)(pa + aoff[2]);
            i32x4 al2 = *(const i32x4*)(pa + aoff[2] + 128);
            i32x4 ah3 = *(const i32x4*)(pa + aoff[3]);
            i32x4 al3 = *(const i32x4*)(pa + aoff[3] + 128);
            __builtin_amdgcn_s_setprio(1);
#pragma unroll
            for (int j = 0; j < 4; j++) {
                acch[2][j] = __builtin_amdgcn_mfma_i32_16x16x64_i8(ah2, bv[j], acch[2][j], 0, 0, 0);
                accl[2][j] = __builtin_amdgcn_mfma_i32_16x16x64_i8(al2, bv[j], accl[2][j], 0, 0, 0);
                acch[3][j] = __builtin_amdgcn_mfma_i32_16x16x64_i8(ah3, bv[j], acch[3][j], 0, 0, 0);
                accl[3][j] = __builtin_amdgcn_mfma_i32_16x16x64_i8(al3, bv[j], accl[3][j], 0, 0, 0);
            }
            __builtin_amdgcn_s_setprio(0);
        }
    }

    // combine hi/lo exactly: prod = acch*128 + accl (per K-half, sums stay < 2^25)
#pragma unroll
    for (int i = 0; i < 4; i++)
#pragma unroll
        for (int j = 0; j < 4; j++)
            acch[i][j] = acch[i][j] * 128 + accl[i][j];

    // K-split pair reduction through LDS (reuse sA as 8 x 8KB slots).
    // wh=0 keeps i=0,1 / gives i=2,3 ; wh=1 keeps i=2,3 / gives i=0,1.
    char* red = &sA[0][0];

#define RED_ST(POS, I)                                                         \
    _Pragma("unroll")                                                          \
    for (int j = 0; j < 4; j++)                                                \
        *(i32x4*)(red + (wave << 13) + ((POS) << 12) + (j << 10) + (lane << 4)) = acch[I][j];

#define RED_LD(POS, I)                                                         \
    _Pragma("unroll")                                                          \
    for (int j = 0; j < 4; j++)                                                \
        acch[I][j] += *(const i32x4*)(red + ((wave ^ 1) << 13) + ((POS) << 12) + (j << 10) + (lane << 4));

    __builtin_amdgcn_s_barrier();          // all loop reads of sA/sB done
    if (wh == 0) { RED_ST(0, 2) RED_ST(1, 3) }
    else         { RED_ST(0, 0) RED_ST(1, 1) }
    asm volatile("s_waitcnt lgkmcnt(0)" ::: "memory");
    __builtin_amdgcn_s_barrier();          // partner's partials visible
    if (wh == 0) { RED_LD(0, 0) RED_LD(1, 1) }
    else         { RED_LD(0, 2) RED_LD(1, 3) }

#define EPI(I)                                                                 \
    {                                                                          \
        const int rb = row0 + (wm << 6) + ((I) << 4) + (quad << 2);            \
        _Pragma("unroll")                                                      \
        for (int j = 0; j < 4; j++) {                                          \
            const int c = col0 + (wn << 6) + (j << 4) + l16;                   \
            _Pragma("unroll")                                                  \
            for (int g = 0; g < 4; g++) {                                      \
                const size_t idx = (size_t)(rb + g) * DIM + c;                 \
                int prod = acch[I][j][g];                                      \
                float y = drive[idx] + (float)prod * (1.0f / 16384.0f);        \
                float sold = (float)((int)Ah[idx] * 128 + (int)Al[idx]) * (1.0f / 16384.0f); \
                float e = __expf(2.0f * y);                                    \
                float th = 1.0f - 2.0f / (e + 1.0f);                           \
                float s = (1.0f - LEAK) * sold + LEAK * th;                    \
                if (write_f32) out[idx] = s;                                   \
                int qz = (int)rintf(s * 16384.f);                              \
                qz = qz > 16383 ? 16383 : (qz < -16383 ? -16383 : qz);         \
                Oh[idx] = (signed char)(qz >> 7);                              \
                Ol[idx] = (signed char)(qz & 127);                             \
            }                                                                  \
        }                                                                      \
    }

    if (wh == 0) { EPI(0) EPI(1) }
    else         { EPI(2) EPI(3) }

#undef RED_ST
#undef RED_LD
#undef EPI
}

extern "C" void kernel_launch(void* const* d_in, const int* in_sizes, int n_in,
                              void* d_out, int out_size, void* d_ws, size_t ws_size,
                              hipStream_t stream) {
    const float* x    = (const float*)d_in[0];
    const float* wgt  = (const float*)d_in[1];
    const float* adj  = (const float*)d_in[2];
    const float* bias = (const float*)d_in[3];
    const float* st0  = (const float*)d_in[4];
    float* out = (float*)d_out;

    const size_t NE = (size_t)DIM * DIM;
    // ws (52 MB): adjT_i8(4) | drive(16) | bufA..bufD bf16(32);
    // i8 state ping-pong (4x4MB) aliases bufA/bufB after drive GEMMs retire.
    signed char* adjT = (signed char*)d_ws;
    float* drive = (float*)(adjT + NE);
    unsigned short* bufA = (unsigned short*)(drive + NE);
    unsigned short* bufB = bufA + NE;
    unsigned short* bufC = bufB + NE;
    unsigned short* bufD = bufC + NE;
    signed char* h1 = (signed char*)bufA;
    signed char* l1 = h1 + NE;
    signed char* h2 = l1 + NE;
    signed char* l2 = h2 + NE;

    dim3 blk(256);
    transpose_split<<<dim3(64, 64), blk, 0, stream>>>(wgt, bufC, bufD);
    split_kernel<<<dim3(4096), blk, 0, stream>>>(x, bufA, bufB);
    transpose_i8<<<dim3(64, 64), blk, 0, stream>>>(adj, adjT);

    gemm_bf16<0><<<dim3(512), blk, 0, stream>>>(bufA, bufB, bufC, (const float*)0,
                                                (const float*)0, drive);
    gemm_bf16<1><<<dim3(512), blk, 0, stream>>>(bufA, bufB, bufD, drive, bias, drive);

    quant_split<<<dim3(4096), blk, 0, stream>>>(st0, h1, l1);

    signed char* hi = h1; signed char* li = l1;
    signed char* ho = h2; signed char* lo = l2;
    for (int t = 0; t < 64; t++) {
        step_i8<<<dim3(256), dim3(512), 0, stream>>>(hi, li, adjT, drive, out,
                                                     ho, lo, (t == 63) ? 1 : 0);
        signed char* th = hi; hi = ho; ho = th;
        signed char* tl = li; li = lo; lo = tl;
    }
}

// Round 2
// 2242.344 us; speedup vs baseline: 1.0566x; 1.0566x over previous
//
#include <hip/hip_runtime.h>

#define DIM 2048
#define LEAK 0.2f

typedef __bf16 bf16x8 __attribute__((ext_vector_type(8)));
typedef float  f32x4  __attribute__((ext_vector_type(4)));
typedef unsigned int u32x4 __attribute__((ext_vector_type(4)));
typedef int    i32x4  __attribute__((ext_vector_type(4)));

static __device__ __forceinline__ unsigned short f2bf(float f) {
    unsigned int x = __float_as_uint(f);
    return (unsigned short)((x + 0x7fffu + ((x >> 16) & 1u)) >> 16);  // RNE
}
static __device__ __forceinline__ float bf2f(unsigned short h) {
    return __uint_as_float(((unsigned int)h) << 16);
}

static __device__ __forceinline__ void async16(const void* g, void* s) {
    __builtin_amdgcn_global_load_lds(
        (const __attribute__((address_space(1))) void*)g,
        (__attribute__((address_space(3))) void*)s, 16, 0, 0);
}

static __device__ __forceinline__ bf16x8 ld_bf16_frag(const char* p) {
    union { u32x4 u; bf16x8 v; } cv;
    cv.u = *(const u32x4*)p;   // ds_read_b128
    return cv.v;
}

// ---------------- prep kernels ----------------

__global__ __launch_bounds__(256) void split_kernel(
    const float* __restrict__ in,
    unsigned short* __restrict__ hi, unsigned short* __restrict__ lo) {
    int idx = blockIdx.x * 256 + threadIdx.x;
    float4 v = ((const float4*)in)[idx];
    ushort4 h, l;
    h.x = f2bf(v.x); l.x = f2bf(v.x - bf2f(h.x));
    h.y = f2bf(v.y); l.y = f2bf(v.y - bf2f(h.y));
    h.z = f2bf(v.z); l.z = f2bf(v.z - bf2f(h.z));
    h.w = f2bf(v.w); l.w = f2bf(v.w - bf2f(h.w));
    ((ushort4*)hi)[idx] = h;
    ((ushort4*)lo)[idx] = l;
}

__global__ __launch_bounds__(256) void transpose_split(
    const float* __restrict__ in,
    unsigned short* __restrict__ hiT, unsigned short* __restrict__ loT) {
    __shared__ float t[32][33];
    int bx = blockIdx.x, by = blockIdx.y;
    int tx = threadIdx.x & 31, ty4 = (threadIdx.x >> 5) << 2;
#pragma unroll
    for (int i = 0; i < 4; i++)
        t[ty4 + i][tx] = in[(size_t)(by * 32 + ty4 + i) * DIM + bx * 32 + tx];
    __syncthreads();
#pragma unroll
    for (int i = 0; i < 4; i++) {
        float v = t[tx][ty4 + i];
        size_t o = (size_t)(bx * 32 + ty4 + i) * DIM + by * 32 + tx;
        unsigned short h = f2bf(v);
        hiT[o] = h;
        loT[o] = f2bf(v - bf2f(h));
    }
}

__global__ __launch_bounds__(256) void transpose_i8(
    const float* __restrict__ in, signed char* __restrict__ outT) {
    __shared__ float t[32][33];
    int bx = blockIdx.x, by = blockIdx.y;
    int tx = threadIdx.x & 31, ty4 = (threadIdx.x >> 5) << 2;
#pragma unroll
    for (int i = 0; i < 4; i++)
        t[ty4 + i][tx] = in[(size_t)(by * 32 + ty4 + i) * DIM + bx * 32 + tx];
    __syncthreads();
#pragma unroll
    for (int i = 0; i < 4; i++)
        outT[(size_t)(bx * 32 + ty4 + i) * DIM + by * 32 + tx] =
            (signed char)t[tx][ty4 + i];
}

__global__ __launch_bounds__(256) void quant_split(
    const float* __restrict__ in,
    signed char* __restrict__ hi, signed char* __restrict__ lo) {
    int idx = blockIdx.x * 256 + threadIdx.x;
    float4 v = ((const float4*)in)[idx];
    char4 h, l;
    {
        int q = (int)rintf(v.x * 16384.f); q = q > 16383 ? 16383 : (q < -16383 ? -16383 : q);
        h.x = (signed char)(q >> 7); l.x = (signed char)(q & 127);
    }
    {
        int q = (int)rintf(v.y * 16384.f); q = q > 16383 ? 16383 : (q < -16383 ? -16383 : q);
        h.y = (signed char)(q >> 7); l.y = (signed char)(q & 127);
    }
    {
        int q = (int)rintf(v.z * 16384.f); q = q > 16383 ? 16383 : (q < -16383 ? -16383 : q);
        h.z = (signed char)(q >> 7); l.z = (signed char)(q & 127);
    }
    {
        int q = (int)rintf(v.w * 16384.f); q = q > 16383 ? 16383 : (q < -16383 ? -16383 : q);
        h.w = (signed char)(q >> 7); l.w = (signed char)(q & 127);
    }
    ((char4*)hi)[idx] = h;
    ((char4*)lo)[idx] = l;
}

// ---------------- bf16 dual-A GEMM (drive), tile 64x128, dbuf ----------------
// MODE 0: Cout = (Ahi+Alo) @ B^T        MODE 1: Cout = Cin + P + bias[n]
// (unchanged from the proven round-0 kernel)
template <int MODE>
__global__ __launch_bounds__(256) void gemm_bf16(
    const unsigned short* __restrict__ Ahi,
    const unsigned short* __restrict__ Alo,
    const unsigned short* __restrict__ BT,
    const float* __restrict__ Cin,
    const float* __restrict__ bias,
    float* __restrict__ Cout) {
    __shared__ alignas(16) char sA[2][16384];
    __shared__ alignas(16) char sB[2][16384];

    const int bid = blockIdx.x;
    const int xcd = bid & 7, slot = bid >> 3;
    const int tm = ((xcd >> 1) << 3) + (slot >> 3);      // 0..31
    const int tn = ((xcd & 1) << 3) + (slot & 7);        // 0..15
    const int row0 = tm << 6, col0 = tn << 7;

    const int tid = threadIdx.x;
    const int lane = tid & 63;
    const int quad = lane >> 4, l16 = lane & 15;
    const int wave = tid >> 6;
    const int wm = wave >> 1, wn = wave & 1;

    const unsigned short* a_src[4]; int a_dst[4];
    const unsigned short* b_src[4]; int b_dst[4];
#pragma unroll
    for (int i = 0; i < 4; i++) {
        int s = tid + 256 * i;                 // 0..1023
        {
            int r = s >> 4, g = (s >> 3) & 1, c = (s & 7) ^ (r & 7);
            a_src[i] = (g ? Alo : Ahi) + (size_t)(row0 + r) * DIM + c * 8;
            a_dst[i] = s * 16;
        }
        {
            int r = s >> 3, c = (s & 7) ^ (r & 7);
            b_src[i] = BT + (size_t)(col0 + r) * DIM + c * 8;
            b_dst[i] = s * 16;
        }
    }

    f32x4 acc[2][4] = {};

    auto stage = [&](int p, int k0) {
#pragma unroll
        for (int i = 0; i < 4; i++) {
            async16(a_src[i] + k0, sA[p] + a_dst[i]);
            async16(b_src[i] + k0, sB[p] + b_dst[i]);
        }
    };

    stage(0, 0);
    __syncthreads();
    for (int it = 0; it < 32; it++) {          // BK = 64 elems (128B)
        const int p = it & 1;
        if (it + 1 < 32) stage(1 - p, (it + 1) * 64);
#pragma unroll
        for (int kk = 0; kk < 2; kk++) {       // two K=32 MFMA phases
            bf16x8 ah[2], al[2], bv[4];
#pragma unroll
            for (int i = 0; i < 2; i++) {
                const int r = (wm << 5) + (i << 4) + l16;
                const int cs = ((kk << 2) + quad) ^ (r & 7);
                ah[i] = ld_bf16_frag(sA[p] + ((r << 4) + cs) * 16);
                al[i] = ld_bf16_frag(sA[p] + ((r << 4) + 8 + cs) * 16);
            }
#pragma unroll
            for (int j = 0; j < 4; j++) {
                const int r = (wn << 6) + (j << 4) + l16;
                const int cs = ((kk << 2) + quad) ^ (r & 7);
                bv[j] = ld_bf16_frag(sB[p] + ((r << 3) + cs) * 16);
            }
#pragma unroll
            for (int i = 0; i < 2; i++)
#pragma unroll
                for (int j = 0; j < 4; j++) {
                    acc[i][j] = __builtin_amdgcn_mfma_f32_16x16x32_bf16(ah[i], bv[j], acc[i][j], 0, 0, 0);
                    acc[i][j] = __builtin_amdgcn_mfma_f32_16x16x32_bf16(al[i], bv[j], acc[i][j], 0, 0, 0);
                }
        }
        __syncthreads();
    }

#pragma unroll
    for (int i = 0; i < 2; i++) {
        const int rb = row0 + (wm << 5) + (i << 4) + (quad << 2);
#pragma unroll
        for (int j = 0; j < 4; j++) {
            const int c = col0 + (wn << 6) + (j << 4) + l16;
#pragma unroll
            for (int g = 0; g < 4; g++) {
                const size_t idx = (size_t)(rb + g) * DIM + c;
                if (MODE == 0) Cout[idx] = acc[i][j][g];
                else           Cout[idx] = Cin[idx] + acc[i][j][g] + bias[c];
            }
        }
    }
}

// ---------------- i8 recurrence step v3: tri-buffer, 2-deep prefetch ----------
// Geometry identical to the proven round-0 kernel: 64x128 tile, 4 waves of
// 32x64, grid 512 = 2 blocks/CU.  Change: BK 128->64 B and THREE LDS buffers
// (48 KB total) so the staging batch for iteration it is issued at it-2 and
// certified by `s_waitcnt vmcnt(4)` at the top of it -- ~2 iterations of
// latency cover, and the barrier never drains in-flight loads (the round-0
// __syncthreads drained vmcnt(0) every iteration = the measured convoy).
// Order is certify-then-publish: each wave waits its OWN batch (vmcnt) BEFORE
// the barrier; after the barrier ALL waves' parts of the buffer are present.
// Stage of buffer (it+2)%3 == (it-1)%3 is issued AFTER the barrier, which also
// certifies everyone finished reading it in iteration it-1.
// LDS layout: sA row = 128 B = 8x16B chunks (hi 0-3 | lo 4-7), slot = L^(r&7)
// -> 2-way bank aliasing (free).  sB row = 64 B = 4 chunks, slot = L^((r>>1)&3)
// -> couples with row parity, 2-way (free).  lo read addr = hi addr XOR 64.
__global__ __launch_bounds__(256, 2) void step_i8(
    const signed char* __restrict__ Ah,
    const signed char* __restrict__ Al,
    const signed char* __restrict__ BT,
    const float* __restrict__ drive,
    float* __restrict__ out,
    signed char* __restrict__ Oh,
    signed char* __restrict__ Ol,
    int write_f32) {
    __shared__ alignas(16) char sA[3][8192];   // 64 rows x 128B
    __shared__ alignas(16) char sB[3][8192];   // 128 rows x 64B

    const int bid = blockIdx.x;
    const int xcd = bid & 7, slot = bid >> 3;
    const int tm = ((xcd >> 1) << 3) + (slot >> 3);      // 0..31
    const int tn = ((xcd & 1) << 3) + (slot & 7);        // 0..15
    const int row0 = tm << 6, col0 = tn << 7;

    const int tid = threadIdx.x;
    const int lane = tid & 63;
    const int quad = lane >> 4, l16 = lane & 15;
    const int wave = tid >> 6;
    const int wm = wave >> 1, wn = wave & 1;

    // staging: 4 x 16B loads/thread (2 A, 2 B) per buffer
    const signed char* a_src[2]; int a_dst[2];
    const signed char* b_src[2]; int b_dst[2];
#pragma unroll
    for (int i = 0; i < 2; i++) {
        int s = tid + 256 * i;                 // A: 0..511 = 64 rows x 8 chunks
        int r = s >> 3, sl = s & 7, L = sl ^ (r & 7);
        a_src[i] = (L < 4 ? Ah : Al) + (size_t)(row0 + r) * DIM + (L & 3) * 16;
        a_dst[i] = s * 16;
    }
#pragma unroll
    for (int i = 0; i < 2; i++) {
        int s = tid + 256 * i;                 // B: 0..511 = 128 rows x 4 chunks
        int r = s >> 2, sl = s & 3, L = sl ^ ((r >> 1) & 3);
        b_src[i] = BT + (size_t)(col0 + r) * DIM + L * 16;
        b_dst[i] = s * 16;
    }

    // per-thread constant LDS read offsets
    int aoffh[2], boff[4];
#pragma unroll
    for (int i = 0; i < 2; i++) {
        int r = (wm << 5) + (i << 4) + l16;
        aoffh[i] = r * 128 + ((quad ^ (r & 7)) << 4);
    }
#pragma unroll
    for (int j = 0; j < 4; j++) {
        int r = (wn << 6) + (j << 4) + l16;
        boff[j] = r * 64 + ((quad ^ ((r >> 1) & 3)) << 4);
    }

    i32x4 acch[2][4] = {};
    i32x4 accl[2][4] = {};

    auto stage = [&](char* ba, char* bb, int k0) {
#pragma unroll
        for (int i = 0; i < 2; i++) async16(a_src[i] + k0, ba + a_dst[i]);
#pragma unroll
        for (int i = 0; i < 2; i++) async16(b_src[i] + k0, bb + b_dst[i]);
    };

    auto compute = [&](const char* pa, const char* pb) {
        i32x4 ah[2], al[2], bv[4];
#pragma unroll
        for (int i = 0; i < 2; i++) {
            ah[i] = *(const i32x4*)(pa + aoffh[i]);
            al[i] = *(const i32x4*)(pa + (aoffh[i] ^ 64));
        }
#pragma unroll
        for (int j = 0; j < 4; j++) bv[j] = *(const i32x4*)(pb + boff[j]);
#pragma unroll
        for (int i = 0; i < 2; i++)
#pragma unroll
            for (int j = 0; j < 4; j++) {
                acch[i][j] = __builtin_amdgcn_mfma_i32_16x16x64_i8(ah[i], bv[j], acch[i][j], 0, 0, 0);
                accl[i][j] = __builtin_amdgcn_mfma_i32_16x16x64_i8(al[i], bv[j], accl[i][j], 0, 0, 0);
            }
    };

    // rotating buffer pointers: at top of iter it, a0/b0 == buffer it%3
    char* a0 = sA[0]; char* a1 = sA[1]; char* a2 = sA[2];
    char* b0 = sB[0]; char* b1 = sB[1]; char* b2 = sB[2];

    // prologue: stage batches for iterations 0 and 1 (8 loads outstanding)
    stage(a0, b0, 0);
    stage(a1, b1, 64);

    for (int it = 0; it < 31; ++it) {          // 32 iters total, last peeled
        asm volatile("s_waitcnt vmcnt(4)" ::: "memory");  // own batch(it) done
        __builtin_amdgcn_s_barrier();                     // publish to all waves
        __builtin_amdgcn_sched_barrier(0);
        if (it < 30) stage(a2, b2, (it + 2) << 6);        // batch(it+2)
        compute(a0, b0);
        char* t;
        t = a0; a0 = a1; a1 = a2; a2 = t;
        t = b0; b0 = b1; b1 = b2; b2 = t;
    }
    asm volatile("s_waitcnt vmcnt(0)" ::: "memory");
    __builtin_amdgcn_s_barrier();
    compute(a0, b0);

    // epilogue: identical to proven round-0 kernel
#pragma unroll
    for (int i = 0; i < 2; i++) {
        const int rb = row0 + (wm << 5) + (i << 4) + (quad << 2);
#pragma unroll
        for (int j = 0; j < 4; j++) {
            const int c = col0 + (wn << 6) + (j << 4) + l16;
#pragma unroll
            for (int g = 0; g < 4; g++) {
                const size_t idx = (size_t)(rb + g) * DIM + c;
                int prod = acch[i][j][g] * 128 + accl[i][j][g];   // exact int
                float y = drive[idx] + (float)prod * (1.0f / 16384.0f);
                float sold = (float)((int)Ah[idx] * 128 + (int)Al[idx]) * (1.0f / 16384.0f);
                float e = __expf(2.0f * y);
                float th = 1.0f - 2.0f / (e + 1.0f);
                float s = (1.0f - LEAK) * sold + LEAK * th;
                if (write_f32) out[idx] = s;
                int q = (int)rintf(s * 16384.f);
                q = q > 16383 ? 16383 : (q < -16383 ? -16383 : q);
                Oh[idx] = (signed char)(q >> 7);
                Ol[idx] = (signed char)(q & 127);
            }
        }
    }
}

extern "C" void kernel_launch(void* const* d_in, const int* in_sizes, int n_in,
                              void* d_out, int out_size, void* d_ws, size_t ws_size,
                              hipStream_t stream) {
    const float* x    = (const float*)d_in[0];
    const float* wgt  = (const float*)d_in[1];
    const float* adj  = (const float*)d_in[2];
    const float* bias = (const float*)d_in[3];
    const float* st0  = (const float*)d_in[4];
    float* out = (float*)d_out;

    const size_t NE = (size_t)DIM * DIM;
    // ws (52 MB): adjT_i8(4) | drive(16) | bufA..bufD bf16(32);
    // i8 state ping-pong (4x4MB) aliases bufA/bufB after drive GEMMs retire.
    signed char* adjT = (signed char*)d_ws;
    float* drive = (float*)(adjT + NE);
    unsigned short* bufA = (unsigned short*)(drive + NE);
    unsigned short* bufB = bufA + NE;
    unsigned short* bufC = bufB + NE;
    unsigned short* bufD = bufC + NE;
    signed char* h1 = (signed char*)bufA;
    signed char* l1 = h1 + NE;
    signed char* h2 = l1 + NE;
    signed char* l2 = h2 + NE;

    dim3 blk(256);
    transpose_split<<<dim3(64, 64), blk, 0, stream>>>(wgt, bufC, bufD);
    split_kernel<<<dim3(4096), blk, 0, stream>>>(x, bufA, bufB);
    transpose_i8<<<dim3(64, 64), blk, 0, stream>>>(adj, adjT);

    gemm_bf16<0><<<dim3(512), blk, 0, stream>>>(bufA, bufB, bufC, (const float*)0,
                                                (const float*)0, drive);
    gemm_bf16<1><<<dim3(512), blk, 0, stream>>>(bufA, bufB, bufD, drive, bias, drive);

    quant_split<<<dim3(4096), blk, 0, stream>>>(st0, h1, l1);

    signed char* hi = h1; signed char* li = l1;
    signed char* ho = h2; signed char* lo = l2;
    for (int t = 0; t < 64; t++) {
        step_i8<<<dim3(512), blk, 0, stream>>>(hi, li, adjT, drive, out,
                                               ho, lo, (t == 63) ? 1 : 0);
        signed char* th = hi; hi = ho; ho = th;
        signed char* tl = li; li = lo; lo = tl;
    }
}